// Round 4
// baseline (10544.095 us; speedup 1.0000x reference)
//
#include <hip/hip_runtime.h>
#include <hip/hip_fp16.h>
#include <cstdint>
#include <cstddef>

#define B_ 64
#define S_ 2048
#define H_ 256
#define E_ 256
#define NG 1024  // 4*H

typedef __attribute__((ext_vector_type(8))) short short8v;
typedef __attribute__((ext_vector_type(4))) float float4v;
typedef __fp16 half2v __attribute__((ext_vector_type(2)));

__device__ __forceinline__ short f2bf(float f) {
  uint32_t u = __float_as_uint(f);
  u = (u + 0x7fffu + ((u >> 16) & 1u)) >> 16;
  return (short)u;
}
__device__ __forceinline__ float sigf(float x) { return 1.f / (1.f + __expf(-x)); }
__device__ __forceinline__ float tanhf_fast(float x) {
  float ax = fabsf(x);
  float e = __expf(-2.f * ax);  // in (0,1], never overflows
  float t = (1.f - e) / (1.f + e);
  return copysignf(t, x);
}
__device__ __forceinline__ uint32_t pkh2(float a, float b) {
  return __builtin_bit_cast(uint32_t, __floats2half2_rn(a, b));
}

// f16-pair dot product with f32 accumulate (v_dot2_f32_f16).
__device__ __forceinline__ float dot2f(uint32_t w, uint32_t h, float acc) {
#if __has_builtin(__builtin_amdgcn_fdot2)
  return __builtin_amdgcn_fdot2(__builtin_bit_cast(half2v, w),
                                __builtin_bit_cast(half2v, h), acc, false);
#else
  __half2 hw = __builtin_bit_cast(__half2, w);
  __half2 hh = __builtin_bit_cast(__half2, h);
  acc = fmaf(__half2float(hw.x), __half2float(hh.x), acc);
  acc = fmaf(__half2float(hw.y), __half2float(hh.y), acc);
  return acc;
#endif
}

// Sum over each 32-lane half of the wave, entirely on the VALU via DPP.
// After this, lane 31 holds sum(lanes 0..31), lane 63 holds sum(lanes 32..63).
__device__ __forceinline__ float red32_dpp(float x) {
  float s = x;
  s += __builtin_bit_cast(float, __builtin_amdgcn_update_dpp(
           0, __builtin_bit_cast(int, s), 0x111, 0xf, 0xf, true));  // row_shr:1
  s += __builtin_bit_cast(float, __builtin_amdgcn_update_dpp(
           0, __builtin_bit_cast(int, s), 0x112, 0xf, 0xf, true));  // row_shr:2
  s += __builtin_bit_cast(float, __builtin_amdgcn_update_dpp(
           0, __builtin_bit_cast(int, s), 0x114, 0xf, 0xf, true));  // row_shr:4
  s += __builtin_bit_cast(float, __builtin_amdgcn_update_dpp(
           0, __builtin_bit_cast(int, s), 0x118, 0xf, 0xf, true));  // row_shr:8
  s += __builtin_bit_cast(float, __builtin_amdgcn_update_dpp(
           0, __builtin_bit_cast(int, s), 0x142, 0xa, 0xf, false)); // row_bcast:15
  return s;
}

// ---------------------------------------------------------------------------
// Phase 1: gate preactivations  pre[m][j] = emb_z[idx[m]] . W_g[j] + b_i + b_h
// M = 64*Cc rows (m = b*Cc + s_local), N = 1024, K = 256. bf16 MFMA 16x16x32.
// Output stored f16.
// ---------------------------------------------------------------------------
__global__ __launch_bounds__(256, 2)
void lstm_xproj(const int* __restrict__ idx, const float* __restrict__ emb,
                const float* __restrict__ w0, const float* __restrict__ w1,
                const float* __restrict__ w2, const float* __restrict__ w3,
                const float* __restrict__ bi0, const float* __restrict__ bi1,
                const float* __restrict__ bi2, const float* __restrict__ bi3,
                const float* __restrict__ bh0, const float* __restrict__ bh1,
                const float* __restrict__ bh2, const float* __restrict__ bh3,
                __half* __restrict__ pre, int s0, int Cc) {
  __shared__ __align__(16) short Ak[4][128][8];  // [kseg][row][8 contiguous k]
  __shared__ __align__(16) short Bk[4][128][8];
  __shared__ int ridx[128];

  const int tid = threadIdx.x;
  const int bm = blockIdx.x, bn = blockIdx.y;
  const int n0 = bn * 128;
  const int g = bn >> 1;            // gate (0..3)
  const int ng = (bn & 1) * 128;    // row base within gate
  const float* wp  = (g == 0) ? w0  : (g == 1) ? w1  : (g == 2) ? w2  : w3;
  const float* bip = (g == 0) ? bi0 : (g == 1) ? bi1 : (g == 2) ? bi2 : bi3;
  const float* bhp = (g == 0) ? bh0 : (g == 1) ? bh1 : (g == 2) ? bh2 : bh3;

  if (tid < 128) {
    int m = bm * 128 + tid;
    int bb = m / Cc;
    int ss = m - bb * Cc;
    ridx[tid] = idx[bb * S_ + s0 + ss];
  }

  float4v z = {0.f, 0.f, 0.f, 0.f};
  float4v acc[4][4];
#pragma unroll
  for (int mi = 0; mi < 4; ++mi)
#pragma unroll
    for (int ni = 0; ni < 4; ++ni) acc[mi][ni] = z;

  const int wv = tid >> 6, lane = tid & 63;
  const int wr = wv >> 1, wc = wv & 1;
  const int lr = lane & 15, ks = lane >> 4;
  const int sr = tid >> 3, seg = tid & 7;

  for (int kt = 0; kt < 8; ++kt) {
    const int k0 = kt * 32;
    __syncthreads();
#pragma unroll
    for (int it = 0; it < 4; ++it) {
      int r = sr + it * 32;
      int tok = ridx[r];
      float4 va = make_float4(0.f, 0.f, 0.f, 0.f);
      if (tok != 0) va = *(const float4*)(emb + (size_t)tok * E_ + k0 + seg * 4);
      short4 sa; sa.x = f2bf(va.x); sa.y = f2bf(va.y); sa.z = f2bf(va.z); sa.w = f2bf(va.w);
      *(short4*)&Ak[seg >> 1][r][(seg & 1) * 4] = sa;
      float4 vb = *(const float4*)(wp + (size_t)(ng + r) * E_ + k0 + seg * 4);
      short4 sb; sb.x = f2bf(vb.x); sb.y = f2bf(vb.y); sb.z = f2bf(vb.z); sb.w = f2bf(vb.w);
      *(short4*)&Bk[seg >> 1][r][(seg & 1) * 4] = sb;
    }
    __syncthreads();
    short8v af[4], bfv[4];
#pragma unroll
    for (int mi = 0; mi < 4; ++mi) af[mi] = *(short8v*)&Ak[ks][wr * 64 + mi * 16 + lr][0];
#pragma unroll
    for (int ni = 0; ni < 4; ++ni) bfv[ni] = *(short8v*)&Bk[ks][wc * 64 + ni * 16 + lr][0];
#pragma unroll
    for (int mi = 0; mi < 4; ++mi)
#pragma unroll
      for (int ni = 0; ni < 4; ++ni)
        acc[mi][ni] = __builtin_amdgcn_mfma_f32_16x16x32_bf16(af[mi], bfv[ni], acc[mi][ni], 0, 0, 0);
  }

#pragma unroll
  for (int ni = 0; ni < 4; ++ni) {
    int jj = ng + wc * 64 + ni * 16 + lr;
    float bias = bip[jj] + bhp[jj];
    int jglob = n0 + wc * 64 + ni * 16 + lr;
#pragma unroll
    for (int mi = 0; mi < 4; ++mi) {
#pragma unroll
      for (int rr = 0; rr < 4; ++rr) {
        int m = bm * 128 + wr * 64 + mi * 16 + (lane >> 4) * 4 + rr;
        pre[(size_t)m * NG + jglob] = __float2half(acc[mi][ni][rr] + bias);
      }
    }
  }
}

// ---------------------------------------------------------------------------
// Phase 2: recurrence. One WG per batch element: 64 WGs x 512 threads.
// amdgpu_waves_per_eu(2,2) forces the regalloc budget to 256 VGPRs/wave so
// the 192 packed-f16 weight dwords (gates i,f,g) actually stay in registers.
// Weight/out pointers are NOT __restrict__ on purpose: the per-step `out`
// stores may alias the weights, so the compiler cannot legally re-load
// (rematerialize) the staged weights inside the step loop.
// Gate o lives in LDS [256][128] dwords, read lane=K (conflict-free),
// reduced across 32 lanes via DPP adds, 1 float/row psum.
// Lane layout: bits 0-2 = jp low, bits 3-4 = q4, bit 5 = jp bit 3.
// ---------------------------------------------------------------------------
__global__ __launch_bounds__(512)
__attribute__((amdgpu_waves_per_eu(2, 2)))
void lstm_rec(const __half* __restrict__ pre,
              const float* wh_i, const float* wh_f,
              const float* wh_g, const float* wh_o,
              const float* __restrict__ h0, const float* __restrict__ c0,
              float* out, float* cstate,
              int s0, int Cc) {
  extern __shared__ char smem[];
  uint32_t* wlds32 = (uint32_t*)smem;                   // o-gate [256][128] dw, 128 KB
  float*    psum   = (float*)(smem + 131072);           // [256] row sums, 1 KB
  uint32_t* hshp   = (uint32_t*)(smem + 131072 + 1024); // [128] packed f16 h pairs

  const int b = blockIdx.x;
  const int t = threadIdx.x;
  const int lane = t & 63, wave = t >> 6;
  const int q4 = (lane >> 3) & 3;                      // K-quarter 0..3
  const int jp = (wave << 4) | ((lane >> 5) << 3) | (lane & 7);  // 0..127
  const int j0 = 2 * jp;
  const bool fin = (q4 == 0);
  const int c32 = t & 31;
  const int rb = t >> 5;                               // 0..15

  // --- stage o-gate into LDS as packed f16 pairs (linear, coalesced) ---
#pragma unroll 8
  for (int i = 0; i < 64; ++i) {
    float2 v = *(const float2*)(wh_o + 2 * (t + 512 * i));
    wlds32[t + 512 * i] = pkh2(v.x, v.y);
  }

  // --- stage i,f,g rows j0, j0+1, K in [64*q4, 64*q4+64) into registers ---
  uint32_t wI0[32], wI1[32], wF0[32], wF1[32], wG0[32], wG1[32];
  {
    const float4* pI0 = (const float4*)(wh_i + (size_t)j0 * 256 + q4 * 64);
    const float4* pI1 = (const float4*)(wh_i + (size_t)(j0 + 1) * 256 + q4 * 64);
    const float4* pF0 = (const float4*)(wh_f + (size_t)j0 * 256 + q4 * 64);
    const float4* pF1 = (const float4*)(wh_f + (size_t)(j0 + 1) * 256 + q4 * 64);
    const float4* pG0 = (const float4*)(wh_g + (size_t)j0 * 256 + q4 * 64);
    const float4* pG1 = (const float4*)(wh_g + (size_t)(j0 + 1) * 256 + q4 * 64);
#pragma unroll
    for (int k = 0; k < 16; ++k) {
      float4 v;
      v = pI0[k]; wI0[2 * k] = pkh2(v.x, v.y); wI0[2 * k + 1] = pkh2(v.z, v.w);
      v = pI1[k]; wI1[2 * k] = pkh2(v.x, v.y); wI1[2 * k + 1] = pkh2(v.z, v.w);
      v = pF0[k]; wF0[2 * k] = pkh2(v.x, v.y); wF0[2 * k + 1] = pkh2(v.z, v.w);
      v = pF1[k]; wF1[2 * k] = pkh2(v.x, v.y); wF1[2 * k + 1] = pkh2(v.z, v.w);
      v = pG0[k]; wG0[2 * k] = pkh2(v.x, v.y); wG0[2 * k + 1] = pkh2(v.z, v.w);
      v = pG1[k]; wG1[2 * k] = pkh2(v.x, v.y); wG1[2 * k + 1] = pkh2(v.z, v.w);
    }
  }
  // Pin the staged weights into registers (defeats demotion to scratch).
#pragma unroll
  for (int k = 0; k < 32; ++k) {
    asm volatile("" : "+v"(wI0[k]), "+v"(wI1[k]), "+v"(wF0[k]),
                      "+v"(wF1[k]), "+v"(wG0[k]), "+v"(wG1[k]));
  }

  // --- init h (packed f16 LDS) and c (registers in finalize lanes) ---
  if (t < 128) {
    float2 hp = (s0 == 0) ? *(const float2*)(h0 + b * H_ + 2 * t)
                          : *(const float2*)(cstate + b * 512 + 256 + 2 * t);
    hshp[t] = pkh2(hp.x, hp.y);
  }
  float cR0 = 0.f, cR1 = 0.f, hN0 = 0.f, hN1 = 0.f;
  if (fin) {
    float2 cv = (s0 == 0) ? *(const float2*)(c0 + b * H_ + j0)
                          : *(const float2*)(cstate + b * 512 + j0);
    cR0 = cv.x; cR1 = cv.y;
  }
  __syncthreads();

  const __half2* pbase = (const __half2*)(pre + (size_t)b * (size_t)Cc * NG);

  for (int tl = 0; tl < Cc; ++tl) {
    // prefetch pre-activations for the j-pair (finalize lanes; hidden by dots)
    float2 pI = {0.f, 0.f}, pF = {0.f, 0.f}, pG = {0.f, 0.f}, pO = {0.f, 0.f};
    if (fin) {
      const __half2* pp = pbase + (size_t)tl * 512;
      pI = __half22float2(pp[jp]);
      pF = __half22float2(pp[128 + jp]);
      pG = __half22float2(pp[256 + jp]);
      pO = __half22float2(pp[384 + jp]);
    }

    // --- o-gate: lane = K-chunk c32, rows rb+16p; conflict-free b128 reads ---
    {
      uint4 hc = *(const uint4*)(hshp + c32 * 4);
      const uint32_t* wl = wlds32 + c32 * 4;
#pragma unroll
      for (int p = 0; p < 16; ++p) {
        int row = rb + 16 * p;
        uint4 wv = *(const uint4*)(wl + row * 128);
        float a = dot2f(wv.x, hc.x, 0.f);
        a = dot2f(wv.y, hc.y, a);
        a = dot2f(wv.z, hc.z, a);
        a = dot2f(wv.w, hc.w, a);
        a = red32_dpp(a);
        if (c32 == 31) psum[row] = a;   // lane31 -> row rb(even), lane63 -> rb(odd)
      }
    }

    // --- register dots: gates i,f,g, rows j0/j0+1, K-quarter q4 ---
    float aI0 = 0.f, aI1 = 0.f, aF0 = 0.f, aF1 = 0.f, aG0 = 0.f, aG1 = 0.f;
    {
      const uint32_t* hq = hshp + q4 * 32;
#pragma unroll
      for (int c8 = 0; c8 < 8; ++c8) {
        uint4 hv = *(const uint4*)(hq + c8 * 4);
        aI0 = dot2f(wI0[c8 * 4 + 0], hv.x, aI0);
        aI0 = dot2f(wI0[c8 * 4 + 1], hv.y, aI0);
        aI0 = dot2f(wI0[c8 * 4 + 2], hv.z, aI0);
        aI0 = dot2f(wI0[c8 * 4 + 3], hv.w, aI0);
        aI1 = dot2f(wI1[c8 * 4 + 0], hv.x, aI1);
        aI1 = dot2f(wI1[c8 * 4 + 1], hv.y, aI1);
        aI1 = dot2f(wI1[c8 * 4 + 2], hv.z, aI1);
        aI1 = dot2f(wI1[c8 * 4 + 3], hv.w, aI1);
        aF0 = dot2f(wF0[c8 * 4 + 0], hv.x, aF0);
        aF0 = dot2f(wF0[c8 * 4 + 1], hv.y, aF0);
        aF0 = dot2f(wF0[c8 * 4 + 2], hv.z, aF0);
        aF0 = dot2f(wF0[c8 * 4 + 3], hv.w, aF0);
        aF1 = dot2f(wF1[c8 * 4 + 0], hv.x, aF1);
        aF1 = dot2f(wF1[c8 * 4 + 1], hv.y, aF1);
        aF1 = dot2f(wF1[c8 * 4 + 2], hv.z, aF1);
        aF1 = dot2f(wF1[c8 * 4 + 3], hv.w, aF1);
        aG0 = dot2f(wG0[c8 * 4 + 0], hv.x, aG0);
        aG0 = dot2f(wG0[c8 * 4 + 1], hv.y, aG0);
        aG0 = dot2f(wG0[c8 * 4 + 2], hv.z, aG0);
        aG0 = dot2f(wG0[c8 * 4 + 3], hv.w, aG0);
        aG1 = dot2f(wG1[c8 * 4 + 0], hv.x, aG1);
        aG1 = dot2f(wG1[c8 * 4 + 1], hv.y, aG1);
        aG1 = dot2f(wG1[c8 * 4 + 2], hv.z, aG1);
        aG1 = dot2f(wG1[c8 * 4 + 3], hv.w, aG1);
      }
    }
    // reduce K-quarters (lane bits 3,4) — stays within 32-lane swizzle range
    aI0 += __shfl_xor(aI0, 8); aI0 += __shfl_xor(aI0, 16);
    aI1 += __shfl_xor(aI1, 8); aI1 += __shfl_xor(aI1, 16);
    aF0 += __shfl_xor(aF0, 8); aF0 += __shfl_xor(aF0, 16);
    aF1 += __shfl_xor(aF1, 8); aF1 += __shfl_xor(aF1, 16);
    aG0 += __shfl_xor(aG0, 8); aG0 += __shfl_xor(aG0, 16);
    aG1 += __shfl_xor(aG1, 8); aG1 += __shfl_xor(aG1, 16);
    __syncthreads();

    if (fin) {
      float2 po2 = *(const float2*)(psum + j0);
      float xi0 = aI0 + pI.x, xi1 = aI1 + pI.y;
      float xf0 = aF0 + pF.x, xf1 = aF1 + pF.y;
      float xg0 = aG0 + pG.x, xg1 = aG1 + pG.y;
      float xo0 = po2.x + pO.x, xo1 = po2.y + pO.y;
      cR0 = sigf(xf0) * cR0 + sigf(xi0) * tanhf_fast(xg0);
      cR1 = sigf(xf1) * cR1 + sigf(xi1) * tanhf_fast(xg1);
      hN0 = sigf(xo0) * tanhf_fast(cR0);
      hN1 = sigf(xo1) * tanhf_fast(cR1);
      *(float2*)(out + ((size_t)b * S_ + (s0 + tl)) * H_ + j0) = make_float2(hN0, hN1);
      hshp[jp] = pkh2(hN0, hN1);
    }
    __syncthreads();
  }

  if (fin) {
    *(float2*)(cstate + b * 512 + j0) = make_float2(cR0, cR1);
    *(float2*)(cstate + b * 512 + 256 + j0) = make_float2(hN0, hN1);
    if (s0 + Cc == S_) {
      float* hfp = out + (size_t)B_ * S_ * H_;
      float* cfp = hfp + (size_t)B_ * H_;
      *(float2*)(hfp + b * H_ + j0) = make_float2(hN0, hN1);
      *(float2*)(cfp + b * H_ + j0) = make_float2(cR0, cR1);
    }
  }
}

// ---------------------------------------------------------------------------
extern "C" void kernel_launch(void* const* d_in, const int* in_sizes, int n_in,
                              void* d_out, int out_size, void* d_ws, size_t ws_size,
                              hipStream_t stream) {
  (void)in_sizes; (void)n_in; (void)out_size;
  const int* idx = (const int*)d_in[0];
  const float* h0 = (const float*)d_in[1];
  const float* c0 = (const float*)d_in[2];
  const float* emb = (const float*)d_in[3];
  const float* w_ii = (const float*)d_in[4];
  const float* w_if = (const float*)d_in[5];
  const float* w_ig = (const float*)d_in[6];
  const float* w_io = (const float*)d_in[7];
  const float* w_hi = (const float*)d_in[8];
  const float* w_hf = (const float*)d_in[9];
  const float* w_hg = (const float*)d_in[10];
  const float* w_ho = (const float*)d_in[11];
  const float* b_ii = (const float*)d_in[12];
  const float* b_if = (const float*)d_in[13];
  const float* b_ig = (const float*)d_in[14];
  const float* b_io = (const float*)d_in[15];
  const float* b_hi = (const float*)d_in[16];
  const float* b_hf = (const float*)d_in[17];
  const float* b_hg = (const float*)d_in[18];
  const float* b_ho = (const float*)d_in[19];
  float* out = (float*)d_out;

  char* ws = (char*)d_ws;
  float* cstate = (float*)ws;                 // 64 * 512 * 4 = 128 KB (c | h)
  __half* pre = (__half*)(ws + 131072);       // rest: f16 preactivations
  size_t avail = (ws_size > 131072) ? ws_size - 131072 : 0;
  long long cmax = (long long)(avail / ((size_t)B_ * NG * sizeof(__half)));
  int C = (int)((cmax > S_) ? S_ : cmax);
  C &= ~1;
  if (C < 2) C = 2;

  const int LDSB = 131072 + 1024 + 512;  // 132608 B
  (void)hipFuncSetAttribute(reinterpret_cast<const void*>(&lstm_rec),
                            hipFuncAttributeMaxDynamicSharedMemorySize, LDSB);

  for (int s0 = 0; s0 < S_; s0 += C) {
    int Cc = (S_ - s0 < C) ? (S_ - s0) : C;
    dim3 gg((unsigned)((64 * Cc) / 128), 8);
    lstm_xproj<<<gg, 256, 0, stream>>>(idx, emb, w_ii, w_if, w_ig, w_io,
                                       b_ii, b_if, b_ig, b_io,
                                       b_hi, b_hf, b_hg, b_ho, pre, s0, Cc);
    lstm_rec<<<64, 512, LDSB, stream>>>(pre, w_hi, w_hf, w_hg, w_ho, h0, c0,
                                        out, cstate, s0, Cc);
  }
}

// Round 5
// 7164.870 us; speedup vs baseline: 1.4716x; 1.4716x over previous
//
#include <hip/hip_runtime.h>
#include <hip/hip_fp16.h>
#include <cstdint>
#include <cstddef>

#define B_ 64
#define S_ 2048
#define H_ 256
#define E_ 256
#define NG 1024  // 4*H

typedef __attribute__((ext_vector_type(8))) short short8v;
typedef __attribute__((ext_vector_type(4))) float float4v;
typedef __fp16 half2v __attribute__((ext_vector_type(2)));

__device__ __forceinline__ short f2bf(float f) {
  uint32_t u = __float_as_uint(f);
  u = (u + 0x7fffu + ((u >> 16) & 1u)) >> 16;
  return (short)u;
}
__device__ __forceinline__ float sigf(float x) { return 1.f / (1.f + __expf(-x)); }
__device__ __forceinline__ float tanhf_fast(float x) {
  float ax = fabsf(x);
  float e = __expf(-2.f * ax);  // in (0,1], never overflows
  float t = (1.f - e) / (1.f + e);
  return copysignf(t, x);
}
__device__ __forceinline__ uint32_t pkh2(float a, float b) {
  return __builtin_bit_cast(uint32_t, __floats2half2_rn(a, b));
}

// f16-pair dot product with f32 accumulate (v_dot2_f32_f16).
__device__ __forceinline__ float dot2f(uint32_t w, uint32_t h, float acc) {
#if __has_builtin(__builtin_amdgcn_fdot2)
  return __builtin_amdgcn_fdot2(__builtin_bit_cast(half2v, w),
                                __builtin_bit_cast(half2v, h), acc, false);
#else
  __half2 hw = __builtin_bit_cast(__half2, w);
  __half2 hh = __builtin_bit_cast(__half2, h);
  acc = fmaf(__half2float(hw.x), __half2float(hh.x), acc);
  acc = fmaf(__half2float(hw.y), __half2float(hh.y), acc);
  return acc;
#endif
}

// Sum over each 32-lane half of the wave, entirely on the VALU via DPP.
// After this, lane 31 holds sum(lanes 0..31), lane 63 holds sum(lanes 32..63).
__device__ __forceinline__ float red32_dpp(float x) {
  float s = x;
  s += __builtin_bit_cast(float, __builtin_amdgcn_update_dpp(
           0, __builtin_bit_cast(int, s), 0x111, 0xf, 0xf, true));  // row_shr:1
  s += __builtin_bit_cast(float, __builtin_amdgcn_update_dpp(
           0, __builtin_bit_cast(int, s), 0x112, 0xf, 0xf, true));  // row_shr:2
  s += __builtin_bit_cast(float, __builtin_amdgcn_update_dpp(
           0, __builtin_bit_cast(int, s), 0x114, 0xf, 0xf, true));  // row_shr:4
  s += __builtin_bit_cast(float, __builtin_amdgcn_update_dpp(
           0, __builtin_bit_cast(int, s), 0x118, 0xf, 0xf, true));  // row_shr:8
  s += __builtin_bit_cast(float, __builtin_amdgcn_update_dpp(
           0, __builtin_bit_cast(int, s), 0x142, 0xa, 0xf, false)); // row_bcast:15
  return s;
}

// ---------------------------------------------------------------------------
// Phase 1: gate preactivations  pre[m][j] = emb_z[idx[m]] . W_g[j] + b_i + b_h
// M = 64*Cc rows (m = b*Cc + s_local), N = 1024, K = 256. bf16 MFMA 16x16x32.
// Output stored f16.
// ---------------------------------------------------------------------------
__global__ __launch_bounds__(256, 2)
void lstm_xproj(const int* __restrict__ idx, const float* __restrict__ emb,
                const float* __restrict__ w0, const float* __restrict__ w1,
                const float* __restrict__ w2, const float* __restrict__ w3,
                const float* __restrict__ bi0, const float* __restrict__ bi1,
                const float* __restrict__ bi2, const float* __restrict__ bi3,
                const float* __restrict__ bh0, const float* __restrict__ bh1,
                const float* __restrict__ bh2, const float* __restrict__ bh3,
                __half* __restrict__ pre, int s0, int Cc) {
  __shared__ __align__(16) short Ak[4][128][8];  // [kseg][row][8 contiguous k]
  __shared__ __align__(16) short Bk[4][128][8];
  __shared__ int ridx[128];

  const int tid = threadIdx.x;
  const int bm = blockIdx.x, bn = blockIdx.y;
  const int n0 = bn * 128;
  const int g = bn >> 1;            // gate (0..3)
  const int ng = (bn & 1) * 128;    // row base within gate
  const float* wp  = (g == 0) ? w0  : (g == 1) ? w1  : (g == 2) ? w2  : w3;
  const float* bip = (g == 0) ? bi0 : (g == 1) ? bi1 : (g == 2) ? bi2 : bi3;
  const float* bhp = (g == 0) ? bh0 : (g == 1) ? bh1 : (g == 2) ? bh2 : bh3;

  if (tid < 128) {
    int m = bm * 128 + tid;
    int bb = m / Cc;
    int ss = m - bb * Cc;
    ridx[tid] = idx[bb * S_ + s0 + ss];
  }

  float4v z = {0.f, 0.f, 0.f, 0.f};
  float4v acc[4][4];
#pragma unroll
  for (int mi = 0; mi < 4; ++mi)
#pragma unroll
    for (int ni = 0; ni < 4; ++ni) acc[mi][ni] = z;

  const int wv = tid >> 6, lane = tid & 63;
  const int wr = wv >> 1, wc = wv & 1;
  const int lr = lane & 15, ks = lane >> 4;
  const int sr = tid >> 3, seg = tid & 7;

  for (int kt = 0; kt < 8; ++kt) {
    const int k0 = kt * 32;
    __syncthreads();
#pragma unroll
    for (int it = 0; it < 4; ++it) {
      int r = sr + it * 32;
      int tok = ridx[r];
      float4 va = make_float4(0.f, 0.f, 0.f, 0.f);
      if (tok != 0) va = *(const float4*)(emb + (size_t)tok * E_ + k0 + seg * 4);
      short4 sa; sa.x = f2bf(va.x); sa.y = f2bf(va.y); sa.z = f2bf(va.z); sa.w = f2bf(va.w);
      *(short4*)&Ak[seg >> 1][r][(seg & 1) * 4] = sa;
      float4 vb = *(const float4*)(wp + (size_t)(ng + r) * E_ + k0 + seg * 4);
      short4 sb; sb.x = f2bf(vb.x); sb.y = f2bf(vb.y); sb.z = f2bf(vb.z); sb.w = f2bf(vb.w);
      *(short4*)&Bk[seg >> 1][r][(seg & 1) * 4] = sb;
    }
    __syncthreads();
    short8v af[4], bfv[4];
#pragma unroll
    for (int mi = 0; mi < 4; ++mi) af[mi] = *(short8v*)&Ak[ks][wr * 64 + mi * 16 + lr][0];
#pragma unroll
    for (int ni = 0; ni < 4; ++ni) bfv[ni] = *(short8v*)&Bk[ks][wc * 64 + ni * 16 + lr][0];
#pragma unroll
    for (int mi = 0; mi < 4; ++mi)
#pragma unroll
      for (int ni = 0; ni < 4; ++ni)
        acc[mi][ni] = __builtin_amdgcn_mfma_f32_16x16x32_bf16(af[mi], bfv[ni], acc[mi][ni], 0, 0, 0);
  }

#pragma unroll
  for (int ni = 0; ni < 4; ++ni) {
    int jj = ng + wc * 64 + ni * 16 + lr;
    float bias = bip[jj] + bhp[jj];
    int jglob = n0 + wc * 64 + ni * 16 + lr;
#pragma unroll
    for (int mi = 0; mi < 4; ++mi) {
#pragma unroll
      for (int rr = 0; rr < 4; ++rr) {
        int m = bm * 128 + wr * 64 + mi * 16 + (lane >> 4) * 4 + rr;
        pre[(size_t)m * NG + jglob] = __float2half(acc[mi][ni][rr] + bias);
      }
    }
  }
}

// ---------------------------------------------------------------------------
// Phase 2: recurrence. One WG per batch element: 64 WGs x 512 threads.
// STATIC __shared__ (132 KB) so the register allocator SEES the LDS
// occupancy constraint (1 WG/CU = 2 waves/SIMD) and budgets 256 VGPRs/wave
// for the 192 archival weight dwords. (Dynamic extern-shared is invisible
// at compile time: the backend assumed LDS=0, targeted 4-8 waves/SIMD, and
// capped VGPRs at 128/64 -> per-step spill reloads = the R2-R4 stall.)
// Weight/out pointers are NOT __restrict__: out stores may alias weights,
// so in-loop re-load of the staged weights is illegal.
// Gate o lives in LDS [256][128] dwords, read lane=K (conflict-free),
// reduced across 32 lanes via DPP adds, 1 float/row psum.
// Lane layout: bits 0-2 = jp low, bits 3-4 = q4, bit 5 = jp bit 3.
// ---------------------------------------------------------------------------
__global__ __launch_bounds__(512, 2)
void lstm_rec(const __half* __restrict__ pre,
              const float* wh_i, const float* wh_f,
              const float* wh_g, const float* wh_o,
              const float* __restrict__ h0, const float* __restrict__ c0,
              float* out, float* cstate,
              int s0, int Cc) {
  __shared__ uint32_t wlds32[256 * 128];  // o-gate packed f16 pairs, 128 KB
  __shared__ float    psum[256];          // o-gate row sums, 1 KB
  __shared__ uint32_t hshp[128];          // packed f16 h pairs, 0.5 KB

  const int b = blockIdx.x;
  const int t = threadIdx.x;
  const int lane = t & 63, wave = t >> 6;
  const int q4 = (lane >> 3) & 3;                      // K-quarter 0..3
  const int jp = (wave << 4) | ((lane >> 5) << 3) | (lane & 7);  // 0..127
  const int j0 = 2 * jp;
  const bool fin = (q4 == 0);
  const int c32 = t & 31;
  const int rb = t >> 5;                               // 0..15

  // --- stage o-gate into LDS as packed f16 pairs (linear, coalesced) ---
#pragma unroll 8
  for (int i = 0; i < 64; ++i) {
    float2 v = *(const float2*)(wh_o + 2 * (t + 512 * i));
    wlds32[t + 512 * i] = pkh2(v.x, v.y);
  }

  // --- stage i,f,g rows j0, j0+1, K in [64*q4, 64*q4+64) into registers ---
  uint32_t wI0[32], wI1[32], wF0[32], wF1[32], wG0[32], wG1[32];
  {
    const float4* pI0 = (const float4*)(wh_i + (size_t)j0 * 256 + q4 * 64);
    const float4* pI1 = (const float4*)(wh_i + (size_t)(j0 + 1) * 256 + q4 * 64);
    const float4* pF0 = (const float4*)(wh_f + (size_t)j0 * 256 + q4 * 64);
    const float4* pF1 = (const float4*)(wh_f + (size_t)(j0 + 1) * 256 + q4 * 64);
    const float4* pG0 = (const float4*)(wh_g + (size_t)j0 * 256 + q4 * 64);
    const float4* pG1 = (const float4*)(wh_g + (size_t)(j0 + 1) * 256 + q4 * 64);
#pragma unroll
    for (int k = 0; k < 16; ++k) {
      float4 v;
      v = pI0[k]; wI0[2 * k] = pkh2(v.x, v.y); wI0[2 * k + 1] = pkh2(v.z, v.w);
      v = pI1[k]; wI1[2 * k] = pkh2(v.x, v.y); wI1[2 * k + 1] = pkh2(v.z, v.w);
      v = pF0[k]; wF0[2 * k] = pkh2(v.x, v.y); wF0[2 * k + 1] = pkh2(v.z, v.w);
      v = pF1[k]; wF1[2 * k] = pkh2(v.x, v.y); wF1[2 * k + 1] = pkh2(v.z, v.w);
      v = pG0[k]; wG0[2 * k] = pkh2(v.x, v.y); wG0[2 * k + 1] = pkh2(v.z, v.w);
      v = pG1[k]; wG1[2 * k] = pkh2(v.x, v.y); wG1[2 * k + 1] = pkh2(v.z, v.w);
    }
  }

  // --- init h (packed f16 LDS) and c (registers in finalize lanes) ---
  if (t < 128) {
    float2 hp = (s0 == 0) ? *(const float2*)(h0 + b * H_ + 2 * t)
                          : *(const float2*)(cstate + b * 512 + 256 + 2 * t);
    hshp[t] = pkh2(hp.x, hp.y);
  }
  float cR0 = 0.f, cR1 = 0.f, hN0 = 0.f, hN1 = 0.f;
  if (fin) {
    float2 cv = (s0 == 0) ? *(const float2*)(c0 + b * H_ + j0)
                          : *(const float2*)(cstate + b * 512 + j0);
    cR0 = cv.x; cR1 = cv.y;
  }
  __syncthreads();

  const __half2* pbase = (const __half2*)(pre + (size_t)b * (size_t)Cc * NG);

  for (int tl = 0; tl < Cc; ++tl) {
    // prefetch pre-activations for the j-pair (finalize lanes; hidden by dots)
    float2 pI = {0.f, 0.f}, pF = {0.f, 0.f}, pG = {0.f, 0.f}, pO = {0.f, 0.f};
    if (fin) {
      const __half2* pp = pbase + (size_t)tl * 512;
      pI = __half22float2(pp[jp]);
      pF = __half22float2(pp[128 + jp]);
      pG = __half22float2(pp[256 + jp]);
      pO = __half22float2(pp[384 + jp]);
    }

    // --- o-gate: lane = K-chunk c32, rows rb+16p; conflict-free b128 reads ---
    {
      uint4 hc = *(const uint4*)(hshp + c32 * 4);
      const uint32_t* wl = wlds32 + c32 * 4;
#pragma unroll
      for (int p = 0; p < 16; ++p) {
        int row = rb + 16 * p;
        uint4 wv = *(const uint4*)(wl + row * 128);
        float a = dot2f(wv.x, hc.x, 0.f);
        a = dot2f(wv.y, hc.y, a);
        a = dot2f(wv.z, hc.z, a);
        a = dot2f(wv.w, hc.w, a);
        a = red32_dpp(a);
        if (c32 == 31) psum[row] = a;   // lane31 -> row rb(even), lane63 -> rb(odd)
      }
    }

    // --- register dots: gates i,f,g, rows j0/j0+1, K-quarter q4 ---
    float aI0 = 0.f, aI1 = 0.f, aF0 = 0.f, aF1 = 0.f, aG0 = 0.f, aG1 = 0.f;
    {
      const uint32_t* hq = hshp + q4 * 32;
#pragma unroll
      for (int c8 = 0; c8 < 8; ++c8) {
        uint4 hv = *(const uint4*)(hq + c8 * 4);
        aI0 = dot2f(wI0[c8 * 4 + 0], hv.x, aI0);
        aI0 = dot2f(wI0[c8 * 4 + 1], hv.y, aI0);
        aI0 = dot2f(wI0[c8 * 4 + 2], hv.z, aI0);
        aI0 = dot2f(wI0[c8 * 4 + 3], hv.w, aI0);
        aI1 = dot2f(wI1[c8 * 4 + 0], hv.x, aI1);
        aI1 = dot2f(wI1[c8 * 4 + 1], hv.y, aI1);
        aI1 = dot2f(wI1[c8 * 4 + 2], hv.z, aI1);
        aI1 = dot2f(wI1[c8 * 4 + 3], hv.w, aI1);
        aF0 = dot2f(wF0[c8 * 4 + 0], hv.x, aF0);
        aF0 = dot2f(wF0[c8 * 4 + 1], hv.y, aF0);
        aF0 = dot2f(wF0[c8 * 4 + 2], hv.z, aF0);
        aF0 = dot2f(wF0[c8 * 4 + 3], hv.w, aF0);
        aF1 = dot2f(wF1[c8 * 4 + 0], hv.x, aF1);
        aF1 = dot2f(wF1[c8 * 4 + 1], hv.y, aF1);
        aF1 = dot2f(wF1[c8 * 4 + 2], hv.z, aF1);
        aF1 = dot2f(wF1[c8 * 4 + 3], hv.w, aF1);
        aG0 = dot2f(wG0[c8 * 4 + 0], hv.x, aG0);
        aG0 = dot2f(wG0[c8 * 4 + 1], hv.y, aG0);
        aG0 = dot2f(wG0[c8 * 4 + 2], hv.z, aG0);
        aG0 = dot2f(wG0[c8 * 4 + 3], hv.w, aG0);
        aG1 = dot2f(wG1[c8 * 4 + 0], hv.x, aG1);
        aG1 = dot2f(wG1[c8 * 4 + 1], hv.y, aG1);
        aG1 = dot2f(wG1[c8 * 4 + 2], hv.z, aG1);
        aG1 = dot2f(wG1[c8 * 4 + 3], hv.w, aG1);
      }
    }
    // reduce K-quarters (lane bits 3,4) — stays within 32-lane swizzle range
    aI0 += __shfl_xor(aI0, 8); aI0 += __shfl_xor(aI0, 16);
    aI1 += __shfl_xor(aI1, 8); aI1 += __shfl_xor(aI1, 16);
    aF0 += __shfl_xor(aF0, 8); aF0 += __shfl_xor(aF0, 16);
    aF1 += __shfl_xor(aF1, 8); aF1 += __shfl_xor(aF1, 16);
    aG0 += __shfl_xor(aG0, 8); aG0 += __shfl_xor(aG0, 16);
    aG1 += __shfl_xor(aG1, 8); aG1 += __shfl_xor(aG1, 16);
    __syncthreads();

    if (fin) {
      float2 po2 = *(const float2*)(psum + j0);
      float xi0 = aI0 + pI.x, xi1 = aI1 + pI.y;
      float xf0 = aF0 + pF.x, xf1 = aF1 + pF.y;
      float xg0 = aG0 + pG.x, xg1 = aG1 + pG.y;
      float xo0 = po2.x + pO.x, xo1 = po2.y + pO.y;
      cR0 = sigf(xf0) * cR0 + sigf(xi0) * tanhf_fast(xg0);
      cR1 = sigf(xf1) * cR1 + sigf(xi1) * tanhf_fast(xg1);
      hN0 = sigf(xo0) * tanhf_fast(cR0);
      hN1 = sigf(xo1) * tanhf_fast(cR1);
      *(float2*)(out + ((size_t)b * S_ + (s0 + tl)) * H_ + j0) = make_float2(hN0, hN1);
      hshp[jp] = pkh2(hN0, hN1);
    }
    __syncthreads();
  }

  if (fin) {
    *(float2*)(cstate + b * 512 + j0) = make_float2(cR0, cR1);
    *(float2*)(cstate + b * 512 + 256 + j0) = make_float2(hN0, hN1);
    if (s0 + Cc == S_) {
      float* hfp = out + (size_t)B_ * S_ * H_;
      float* cfp = hfp + (size_t)B_ * H_;
      *(float2*)(hfp + b * H_ + j0) = make_float2(hN0, hN1);
      *(float2*)(cfp + b * H_ + j0) = make_float2(cR0, cR1);
    }
  }
}

// ---------------------------------------------------------------------------
extern "C" void kernel_launch(void* const* d_in, const int* in_sizes, int n_in,
                              void* d_out, int out_size, void* d_ws, size_t ws_size,
                              hipStream_t stream) {
  (void)in_sizes; (void)n_in; (void)out_size;
  const int* idx = (const int*)d_in[0];
  const float* h0 = (const float*)d_in[1];
  const float* c0 = (const float*)d_in[2];
  const float* emb = (const float*)d_in[3];
  const float* w_ii = (const float*)d_in[4];
  const float* w_if = (const float*)d_in[5];
  const float* w_ig = (const float*)d_in[6];
  const float* w_io = (const float*)d_in[7];
  const float* w_hi = (const float*)d_in[8];
  const float* w_hf = (const float*)d_in[9];
  const float* w_hg = (const float*)d_in[10];
  const float* w_ho = (const float*)d_in[11];
  const float* b_ii = (const float*)d_in[12];
  const float* b_if = (const float*)d_in[13];
  const float* b_ig = (const float*)d_in[14];
  const float* b_io = (const float*)d_in[15];
  const float* b_hi = (const float*)d_in[16];
  const float* b_hf = (const float*)d_in[17];
  const float* b_hg = (const float*)d_in[18];
  const float* b_ho = (const float*)d_in[19];
  float* out = (float*)d_out;

  char* ws = (char*)d_ws;
  float* cstate = (float*)ws;                 // 64 * 512 * 4 = 128 KB (c | h)
  __half* pre = (__half*)(ws + 131072);       // rest: f16 preactivations
  size_t avail = (ws_size > 131072) ? ws_size - 131072 : 0;
  long long cmax = (long long)(avail / ((size_t)B_ * NG * sizeof(__half)));
  int C = (int)((cmax > S_) ? S_ : cmax);
  C &= ~1;
  if (C < 2) C = 2;

  for (int s0 = 0; s0 < S_; s0 += C) {
    int Cc = (S_ - s0 < C) ? (S_ - s0) : C;
    dim3 gg((unsigned)((64 * Cc) / 128), 8);
    lstm_xproj<<<gg, 256, 0, stream>>>(idx, emb, w_ii, w_if, w_ig, w_io,
                                       b_ii, b_if, b_ig, b_io,
                                       b_hi, b_hf, b_hg, b_ho, pre, s0, Cc);
    lstm_rec<<<64, 512, 0, stream>>>(pre, w_hi, w_hf, w_hg, w_ho, h0, c0,
                                     out, cstate, s0, Cc);
  }
}